// Round 1
// baseline (872.856 us; speedup 1.0000x reference)
//
#include <hip/hip_runtime.h>

typedef __attribute__((ext_vector_type(4))) float f32x4;
typedef __attribute__((ext_vector_type(8))) short bf16x8;

// LDS byte offsets
#define XS 0        // xs_t[64 tok][256 c] bf16, 32KB, swizzled rows (512B)
#define AT 32768    // attn_t[64 tok][256 c] bf16, 32KB, same layout
#define QO 65536    // q_l[64 tok][32 d] bf16, 4KB (64B rows)
#define KO 69632    // k_l[64 tok][32 d] bf16, 4KB
#define PO 65536    // p_l[64 i][64 j] bf16, 8KB (128B rows) -- ALIASES q_l+k_l
#define VO 73728    // v_l[32 d][64 tok] bf16, 4KB (128B rows)
#define LDS_SZ 77824

__device__ __forceinline__ unsigned short f2bf(float f) {
  unsigned int u = __float_as_uint(f);
  return (unsigned short)((u + 0x7FFFu + ((u >> 16) & 1u)) >> 16);
}
__device__ __forceinline__ unsigned int pack2(float a, float b) {
  return (unsigned int)f2bf(a) | ((unsigned int)f2bf(b) << 16);
}
// 512B-row buffers (xs_t, attn_t): XOR bits 4..6 with (tok ^ tok>>3)
__device__ __forceinline__ int xsw(int base, int tok, int cb) {
  return (base + tok * 512 + cb) ^ ((((tok >> 3) ^ tok) & 7) << 4);
}
// 64B-row buffers (q_l, k_l): XOR bits 4..5 with (tok>>1)&3
__device__ __forceinline__ int qsw(int base, int tok, int db) {
  return (base + tok * 64 + db) ^ (((tok >> 1) & 3) << 4);
}
// 128B-row buffers (v_l, p_l): XOR bits 4..6 with (row ^ row>>3)
__device__ __forceinline__ int vsw(int base, int row, int cb) {
  return (base + row * 128 + cb) ^ ((((row >> 3) ^ row) & 7) << 4);
}

__global__ void convw_kernel(const float* __restrict__ wqkv,
                             const float* __restrict__ wout,
                             unsigned short* __restrict__ dst) {
  int i = blockIdx.x * 256 + threadIdx.x;
  if (i < 196608) dst[i] = f2bf(wqkv[i]);
  if (i < 65536) dst[196608 + i] = f2bf(wout[i]);
}

__global__ __launch_bounds__(256, 2) void wattn_kernel(
    const float* __restrict__ x, const unsigned short* __restrict__ wqkv,
    const unsigned short* __restrict__ wout, const float* __restrict__ bo,
    float* __restrict__ y) {
  __shared__ __align__(16) char lds[LDS_SZ];

  const int tid = threadIdx.x;
  const int l = tid & 63;
  const int w = tid >> 6;      // wave id 0..3
  const int lo = l & 15;
  const int dg = l >> 4;       // 4-lane group 0..3

  // XCD-chunked swizzle: consecutive windows (sharing cache lines) -> same XCD
  const int bid = blockIdx.x;
  const int rw = ((bid & 7) << 9) | (bid >> 3);   // 4096 = 8*512, bijective
  const int b = rw >> 10;
  const int rem = rw & 1023;
  const int wy = rem >> 5;
  const int wx = rem & 31;

  const size_t wbase = ((size_t)b * 65536 + (size_t)wy * 8) * 256 + (size_t)wx * 8;
  const float* xw = x + wbase;
  float* yw = y + wbase;

  // ---- stage x window -> xs_t[tok][c] (bf16, channel-contiguous) ----
  {
    const int irow = lo >> 1;
    const int jq = lo & 1;
    const float* xp = xw + irow * 256 + jq * 4;
    const int tok0 = irow * 8 + jq * 4;
#pragma unroll
    for (int cc = 0; cc < 4; ++cc) {
      const int cb = w * 64 + cc * 16 + dg * 4;
      f32x4 v0 = *(const f32x4*)(xp + (size_t)(cb + 0) * 65536);
      f32x4 v1 = *(const f32x4*)(xp + (size_t)(cb + 1) * 65536);
      f32x4 v2 = *(const f32x4*)(xp + (size_t)(cb + 2) * 65536);
      f32x4 v3 = *(const f32x4*)(xp + (size_t)(cb + 3) * 65536);
#pragma unroll
      for (int t = 0; t < 4; ++t) {
        uint2 uu;
        uu.x = pack2(v0[t], v1[t]);
        uu.y = pack2(v2[t], v3[t]);
        *(uint2*)(lds + xsw(XS, tok0 + t, cb * 2)) = uu;
      }
    }
  }
  __syncthreads();

  const float lscale = 0.17677669529663687f * 1.4426950408889634f; // d^-0.5 * log2(e)

#pragma unroll 1
  for (int h = 0; h < 8; ++h) {
    // B-fragments of x for this wave's token tile (nt == w), cached in regs
    bf16x8 xf[8];
#pragma unroll
    for (int kk = 0; kk < 8; ++kk)
      xf[kk] = *(const bf16x8*)(lds + xsw(XS, w * 16 + lo, kk * 64 + dg * 16));

    // ---- QKV projection for head h: D = W_p[h] @ x ----
#pragma unroll
    for (int pm = 0; pm < 6; ++pm) {
      const int p = pm >> 1;   // 0=q 1=k 2=v
      const int mt = pm & 1;   // d-halftile
      const int orow = p * 256 + h * 32 + mt * 16 + lo;
      const unsigned short* wr = wqkv + orow * 256 + dg * 8;
      f32x4 acc = {0.f, 0.f, 0.f, 0.f};
#pragma unroll
      for (int kk = 0; kk < 8; ++kk) {
        bf16x8 af = *(const bf16x8*)(wr + kk * 32);
        acc = __builtin_amdgcn_mfma_f32_16x16x32_bf16(af, xf[kk], acc, 0, 0, 0);
      }
      const int tok = w * 16 + lo;   // acc col = token
      if (p < 2) {
        // q_l/k_l[tok][d]: 4 consecutive d (regs) -> one b64 write
        uint2 uu;
        uu.x = pack2(acc[0], acc[1]);
        uu.y = pack2(acc[2], acc[3]);
        *(uint2*)(lds + qsw(p == 0 ? QO : KO, tok, mt * 32 + dg * 8)) = uu;
      } else {
        // v_l[d][tok]: scattered b16 writes
#pragma unroll
        for (int t = 0; t < 4; ++t) {
          const int d = mt * 16 + dg * 4 + t;
          *(unsigned short*)(lds + vsw(VO, d, tok * 2)) = f2bf(acc[t]);
        }
      }
    }
    __syncthreads();  // bar1: q/k/v visible

    // ---- S^T = K^T @ Q  (wave w owns column block i in [16w,16w+16)) ----
    bf16x8 qf = *(const bf16x8*)(lds + qsw(QO, w * 16 + lo, dg * 16));
    f32x4 st[4];
#pragma unroll
    for (int jt = 0; jt < 4; ++jt) {
      bf16x8 kf = *(const bf16x8*)(lds + qsw(KO, jt * 16 + lo, dg * 16));
      f32x4 z = {0.f, 0.f, 0.f, 0.f};
      st[jt] = __builtin_amdgcn_mfma_f32_16x16x32_bf16(kf, qf, z, 0, 0, 0);
    }
    // softmax over j (rows of S^T): 16 in-lane + lanes^16,^32
    float m = st[0][0];
#pragma unroll
    for (int jt = 0; jt < 4; ++jt)
#pragma unroll
      for (int t = 0; t < 4; ++t) m = fmaxf(m, st[jt][t]);
    m = fmaxf(m, __shfl_xor(m, 16, 64));
    m = fmaxf(m, __shfl_xor(m, 32, 64));
    float s = 0.f;
#pragma unroll
    for (int jt = 0; jt < 4; ++jt)
#pragma unroll
      for (int t = 0; t < 4; ++t) {
        float e = exp2f((st[jt][t] - m) * lscale);
        st[jt][t] = e;
        s += e;
      }
    s += __shfl_xor(s, 16, 64);
    s += __shfl_xor(s, 32, 64);
    const float rs = 1.0f / s;   // per-column-i, lane-local through PV
    __syncthreads();  // bar2: all q/k reads done before p writes (p aliases q/k)

    const int it = w * 16 + lo;
    // p_l[i][j] (unnormalized P, wave-private rows)
#pragma unroll
    for (int jt = 0; jt < 4; ++jt) {
      uint2 uu;
      uu.x = pack2(st[jt][0], st[jt][1]);
      uu.y = pack2(st[jt][2], st[jt][3]);
      *(uint2*)(lds + vsw(PO, it, jt * 32 + dg * 8)) = uu;
    }
    // ---- out^T = V @ P^T ----
    f32x4 o0 = {0.f, 0.f, 0.f, 0.f};
    f32x4 o1 = {0.f, 0.f, 0.f, 0.f};
#pragma unroll
    for (int kk = 0; kk < 2; ++kk) {
      bf16x8 pf = *(const bf16x8*)(lds + vsw(PO, it, kk * 64 + dg * 16));
      bf16x8 vf0 = *(const bf16x8*)(lds + vsw(VO, lo, kk * 64 + dg * 16));
      bf16x8 vf1 = *(const bf16x8*)(lds + vsw(VO, 16 + lo, kk * 64 + dg * 16));
      o0 = __builtin_amdgcn_mfma_f32_16x16x32_bf16(vf0, pf, o0, 0, 0, 0);
      o1 = __builtin_amdgcn_mfma_f32_16x16x32_bf16(vf1, pf, o1, 0, 0, 0);
    }
    // normalize + write attn_t[tok=i][c = h*32 + d]
    {
      uint2 uu;
      uu.x = pack2(o0[0] * rs, o0[1] * rs);
      uu.y = pack2(o0[2] * rs, o0[3] * rs);
      *(uint2*)(lds + xsw(AT, it, h * 64 + dg * 8)) = uu;
      uu.x = pack2(o1[0] * rs, o1[1] * rs);
      uu.y = pack2(o1[2] * rs, o1[3] * rs);
      *(uint2*)(lds + xsw(AT, it, h * 64 + 32 + dg * 8)) = uu;
    }
    __syncthreads();  // bar3: before next head clobbers q/k/v (and p alias)
  }

  // ---- final projection Y = Wout @ attn (+ bias) ----
#pragma unroll 1
  for (int mt4 = 0; mt4 < 4; ++mt4) {
    const int mt = w * 4 + mt4;
    const unsigned short* wr = wout + (mt * 16 + lo) * 256 + dg * 8;
    f32x4 acc0 = {0.f, 0.f, 0.f, 0.f};
    f32x4 acc1 = {0.f, 0.f, 0.f, 0.f};
    f32x4 acc2 = {0.f, 0.f, 0.f, 0.f};
    f32x4 acc3 = {0.f, 0.f, 0.f, 0.f};
#pragma unroll
    for (int kk = 0; kk < 8; ++kk) {
      bf16x8 af = *(const bf16x8*)(wr + kk * 32);
      bf16x8 b0 = *(const bf16x8*)(lds + xsw(AT, 0 + lo, kk * 64 + dg * 16));
      bf16x8 b1 = *(const bf16x8*)(lds + xsw(AT, 16 + lo, kk * 64 + dg * 16));
      bf16x8 b2 = *(const bf16x8*)(lds + xsw(AT, 32 + lo, kk * 64 + dg * 16));
      bf16x8 b3 = *(const bf16x8*)(lds + xsw(AT, 48 + lo, kk * 64 + dg * 16));
      acc0 = __builtin_amdgcn_mfma_f32_16x16x32_bf16(af, b0, acc0, 0, 0, 0);
      acc1 = __builtin_amdgcn_mfma_f32_16x16x32_bf16(af, b1, acc1, 0, 0, 0);
      acc2 = __builtin_amdgcn_mfma_f32_16x16x32_bf16(af, b2, acc2, 0, 0, 0);
      acc3 = __builtin_amdgcn_mfma_f32_16x16x32_bf16(af, b3, acc3, 0, 0, 0);
    }
    f32x4 bo4 = *(const f32x4*)(bo + mt * 16 + dg * 4);
    f32x4 accs[4] = {acc0, acc1, acc2, acc3};
#pragma unroll
    for (int nt = 0; nt < 4; ++nt) {
#pragma unroll
      for (int t = 0; t < 4; ++t) {
        const int o_ = mt * 16 + dg * 4 + t;
        const int tok = nt * 16 + lo;
        yw[(size_t)o_ * 65536 + (size_t)(tok >> 3) * 256 + (tok & 7)] =
            accs[nt][t] + bo4[t];
      }
    }
  }
}

extern "C" void kernel_launch(void* const* d_in, const int* in_sizes, int n_in,
                              void* d_out, int out_size, void* d_ws, size_t ws_size,
                              hipStream_t stream) {
  const float* x = (const float*)d_in[0];
  const float* wqkv = (const float*)d_in[1];
  const float* wout = (const float*)d_in[2];
  const float* bo = (const float*)d_in[3];
  float* y = (float*)d_out;
  unsigned short* wbf = (unsigned short*)d_ws;

  convw_kernel<<<768, 256, 0, stream>>>(wqkv, wout, wbf);
  wattn_kernel<<<4096, 256, 0, stream>>>(x, wbf, wbf + 196608, bo, y);
}

// Round 2
// 476.260 us; speedup vs baseline: 1.8327x; 1.8327x over previous
//
#include <hip/hip_runtime.h>

typedef __attribute__((ext_vector_type(4))) float f32x4;
typedef __attribute__((ext_vector_type(8))) short bf16x8;

#define MFMA __builtin_amdgcn_mfma_f32_16x16x32_bf16

// LDS map: XS [64 tok][512B] at 0 (32KB, shared).
// Per-wave scratch at 32768 + w*12288 (12KB):
//   q_l [64][64B] at +0, k_l [64][64B] at +4096, v_l [32][128B] at +8192
//   p_l [64][128B] aliases q+k (+0..8192)
//   at_w [64][128B] aliases +0..8192 after head loop (out held in regs until then)
#define SCW 12288
#define LDS_SZ 81920

__device__ __forceinline__ unsigned short f2bf(float f) {
  unsigned int u = __float_as_uint(f);
  return (unsigned short)((u + 0x7FFFu + ((u >> 16) & 1u)) >> 16);
}
__device__ __forceinline__ unsigned int pack2(float a, float b) {
  return (unsigned int)f2bf(a) | ((unsigned int)f2bf(b) << 16);
}
__device__ __forceinline__ uint2 pack4(f32x4 v) {
  uint2 u;
  u.x = pack2(v[0], v[1]);
  u.y = pack2(v[2], v[3]);
  return u;
}
// 512B-row buffer (xs): XOR byte bits 4..6
__device__ __forceinline__ int xsw(int tok, int cb) {
  return (tok * 512 + cb) ^ ((((tok >> 3) ^ tok) & 7) << 4);
}
// 64B-row buffers (q_l, k_l)
__device__ __forceinline__ int qsw(int base, int row, int b) {
  return (base + row * 64 + b) ^ (((row >> 1) & 3) << 4);
}
// 128B-row buffers (v_l, p_l, at)
__device__ __forceinline__ int vsw(int base, int row, int b) {
  return (base + row * 128 + b) ^ ((row & 7) << 4);
}

__global__ void convw_kernel(const float* __restrict__ wqkv,
                             const float* __restrict__ wout,
                             unsigned short* __restrict__ dst) {
  int i = blockIdx.x * 256 + threadIdx.x;
  if (i < 196608) dst[i] = f2bf(wqkv[i]);
  if (i < 65536) dst[196608 + i] = f2bf(wout[i]);
}

__global__ __launch_bounds__(256, 2) void wattn_kernel(
    const float* __restrict__ x, const unsigned short* __restrict__ wqkv,
    const unsigned short* __restrict__ wout, const float* __restrict__ bo,
    float* __restrict__ y) {
  __shared__ __align__(16) char lds[LDS_SZ];

  const int tid = threadIdx.x;
  const int l = tid & 63;
  const int w = tid >> 6;      // wave 0..3
  const int lo = l & 15;
  const int dg = l >> 4;       // 0..3

  // XCD-chunked block swizzle (bijective: 4096 = 8*512)
  const int bid = blockIdx.x;
  const int rw = ((bid & 7) << 9) | (bid >> 3);
  const int b = rw >> 10;
  const int rem = rw & 1023;
  const int wy = rem >> 5;
  const int wx = rem & 31;

  const size_t wbase = ((size_t)b * 65536 + (size_t)wy * 8) * 256 + (size_t)wx * 8;
  const float* xw = x + wbase;
  float* yw = y + wbase;

  // ---- stage x window -> xs[tok][c] bf16 ----
  {
    const int irow = lo >> 1;
    const int jq = lo & 1;
    const float* xp = xw + irow * 256 + jq * 4;
    const int tok0 = irow * 8 + jq * 4;
#pragma unroll
    for (int cc = 0; cc < 4; ++cc) {
      const int cb = w * 64 + cc * 16 + dg * 4;
      f32x4 v0 = *(const f32x4*)(xp + (size_t)(cb + 0) * 65536);
      f32x4 v1 = *(const f32x4*)(xp + (size_t)(cb + 1) * 65536);
      f32x4 v2 = *(const f32x4*)(xp + (size_t)(cb + 2) * 65536);
      f32x4 v3 = *(const f32x4*)(xp + (size_t)(cb + 3) * 65536);
#pragma unroll
      for (int t = 0; t < 4; ++t) {
        uint2 uu;
        uu.x = pack2(v0[t], v1[t]);
        uu.y = pack2(v2[t], v3[t]);
        *(uint2*)(lds + xsw(tok0 + t, cb * 2)) = uu;
      }
    }
  }
  __syncthreads();   // barrier 1 of 2

  const float lscale = 0.17677669529663687f * 1.4426950408889634f;
  const int SB = 32768 + w * SCW;

  f32x4 out[2][2][4];   // [hh][dt][it] out^T[d][i], held in regs until AT write

#pragma unroll
  for (int hh = 0; hh < 2; ++hh) {
    const int h = w * 2 + hh;
    const unsigned short* wp0 = wqkv + (size_t)(h * 32 + lo) * 256 + dg * 8;

    // ---- QKV projection: 24 independent MFMA chains per kk ----
    f32x4 qa[2][4], ka[2][4], va[4][2];
#pragma unroll
    for (int dt = 0; dt < 2; ++dt)
#pragma unroll
      for (int it = 0; it < 4; ++it) {
        qa[dt][it] = {0.f, 0.f, 0.f, 0.f};
        ka[dt][it] = {0.f, 0.f, 0.f, 0.f};
        va[it][dt] = {0.f, 0.f, 0.f, 0.f};
      }
#pragma unroll
    for (int kk = 0; kk < 8; ++kk) {
      bf16x8 xf[4];
#pragma unroll
      for (int it = 0; it < 4; ++it)
        xf[it] = *(const bf16x8*)(lds + xsw(it * 16 + lo, kk * 64 + dg * 16));
      bf16x8 wq0 = *(const bf16x8*)(wp0 + kk * 32);
      bf16x8 wq1 = *(const bf16x8*)(wp0 + 4096 + kk * 32);
      bf16x8 wk0 = *(const bf16x8*)(wp0 + 65536 + kk * 32);
      bf16x8 wk1 = *(const bf16x8*)(wp0 + 69632 + kk * 32);
      bf16x8 wv0 = *(const bf16x8*)(wp0 + 131072 + kk * 32);
      bf16x8 wv1 = *(const bf16x8*)(wp0 + 135168 + kk * 32);
#pragma unroll
      for (int it = 0; it < 4; ++it) {
        qa[0][it] = MFMA(wq0, xf[it], qa[0][it], 0, 0, 0);  // acc q[d][tok]
        qa[1][it] = MFMA(wq1, xf[it], qa[1][it], 0, 0, 0);
        ka[0][it] = MFMA(wk0, xf[it], ka[0][it], 0, 0, 0);
        ka[1][it] = MFMA(wk1, xf[it], ka[1][it], 0, 0, 0);
        va[it][0] = MFMA(xf[it], wv0, va[it][0], 0, 0, 0);  // acc v^T[tok][d]
        va[it][1] = MFMA(xf[it], wv1, va[it][1], 0, 0, 0);
      }
    }
    // stores: q_l[tok][d], k_l[tok][d], v_l[d][tok] — all uint2
#pragma unroll
    for (int dt = 0; dt < 2; ++dt)
#pragma unroll
      for (int it = 0; it < 4; ++it) {
        *(uint2*)(lds + qsw(SB, it * 16 + lo, dt * 32 + dg * 8)) = pack4(qa[dt][it]);
        *(uint2*)(lds + qsw(SB + 4096, it * 16 + lo, dt * 32 + dg * 8)) = pack4(ka[dt][it]);
        *(uint2*)(lds + vsw(SB + 8192, dt * 16 + lo, it * 32 + dg * 8)) = pack4(va[it][dt]);
      }

    // ---- S^T = mfma(K-frag, Q-frag): acc row=j (in-reg), col=i (lane) ----
    bf16x8 qf[4], kf[4];
#pragma unroll
    for (int it = 0; it < 4; ++it)
      qf[it] = *(const bf16x8*)(lds + qsw(SB, it * 16 + lo, dg * 16));
#pragma unroll
    for (int jt = 0; jt < 4; ++jt)
      kf[jt] = *(const bf16x8*)(lds + qsw(SB + 4096, jt * 16 + lo, dg * 16));
    f32x4 st[4][4];
#pragma unroll
    for (int jt = 0; jt < 4; ++jt)
#pragma unroll
      for (int it = 0; it < 4; ++it) {
        f32x4 z = {0.f, 0.f, 0.f, 0.f};
        st[jt][it] = MFMA(kf[jt], qf[it], z, 0, 0, 0);
      }
    // softmax over j: 16 in-lane + shfl_xor 16,32 (per i-tile, independent)
    float rs[4];
#pragma unroll
    for (int it = 0; it < 4; ++it) {
      float m = st[0][it][0];
#pragma unroll
      for (int jt = 0; jt < 4; ++jt)
#pragma unroll
        for (int t = 0; t < 4; ++t) m = fmaxf(m, st[jt][it][t]);
      m = fmaxf(m, __shfl_xor(m, 16, 64));
      m = fmaxf(m, __shfl_xor(m, 32, 64));
      float s = 0.f;
#pragma unroll
      for (int jt = 0; jt < 4; ++jt)
#pragma unroll
        for (int t = 0; t < 4; ++t) {
          float e = exp2f((st[jt][it][t] - m) * lscale);
          st[jt][it][t] = e;
          s += e;
        }
      s += __shfl_xor(s, 16, 64);
      s += __shfl_xor(s, 32, 64);
      rs[it] = 1.0f / s;
    }
    // p_l[i][j] store (aliases q+k; same-wave DS order is safe)
#pragma unroll
    for (int jt = 0; jt < 4; ++jt)
#pragma unroll
      for (int it = 0; it < 4; ++it)
        *(uint2*)(lds + vsw(SB, it * 16 + lo, jt * 32 + dg * 8)) = pack4(st[jt][it]);

    // ---- PV: out^T = V^T @ P^T ----
    bf16x8 vf[2][2];
#pragma unroll
    for (int dt = 0; dt < 2; ++dt)
#pragma unroll
      for (int kp = 0; kp < 2; ++kp)
        vf[dt][kp] = *(const bf16x8*)(lds + vsw(SB + 8192, dt * 16 + lo, kp * 64 + dg * 16));
#pragma unroll
    for (int it = 0; it < 4; ++it) {
      bf16x8 pf0 = *(const bf16x8*)(lds + vsw(SB, it * 16 + lo, dg * 16));
      bf16x8 pf1 = *(const bf16x8*)(lds + vsw(SB, it * 16 + lo, 64 + dg * 16));
#pragma unroll
      for (int dt = 0; dt < 2; ++dt) {
        f32x4 z = {0.f, 0.f, 0.f, 0.f};
        f32x4 o = MFMA(vf[dt][0], pf0, z, 0, 0, 0);
        o = MFMA(vf[dt][1], pf1, o, 0, 0, 0);
        o *= rs[it];
        out[hh][dt][it] = o;
      }
    }
  }

  // ---- write attn-out to own scratch region (wave-private alias, no sync) ----
#pragma unroll
  for (int hh = 0; hh < 2; ++hh)
#pragma unroll
    for (int dt = 0; dt < 2; ++dt)
#pragma unroll
      for (int it = 0; it < 4; ++it)
        *(uint2*)(lds + vsw(SB, it * 16 + lo, hh * 64 + dt * 32 + dg * 8)) =
            pack4(out[hh][dt][it]);
  __syncthreads();   // barrier 2 of 2

  // ---- final projection: Y^T = attn @ Wout^T for o in [w*64, w*64+64) ----
  const unsigned short* wo0 = wout + (size_t)(w * 64 + lo) * 256 + dg * 8;
  f32x4 ya[4][4];
#pragma unroll
  for (int ot = 0; ot < 4; ++ot)
#pragma unroll
    for (int it = 0; it < 4; ++it) ya[ot][it] = {0.f, 0.f, 0.f, 0.f};
#pragma unroll
  for (int kk = 0; kk < 8; ++kk) {
    bf16x8 bt[4];
#pragma unroll
    for (int it = 0; it < 4; ++it)
      bt[it] = *(const bf16x8*)(lds + vsw(32768 + (kk >> 1) * SCW, it * 16 + lo,
                                          (kk & 1) * 64 + dg * 16));
    bf16x8 wf[4];
#pragma unroll
    for (int ot = 0; ot < 4; ++ot)
      wf[ot] = *(const bf16x8*)(wo0 + ot * 4096 + kk * 32);
#pragma unroll
    for (int ot = 0; ot < 4; ++ot)
#pragma unroll
      for (int it = 0; it < 4; ++it)
        ya[ot][it] = MFMA(bt[it], wf[ot], ya[ot][it], 0, 0, 0);
  }
#pragma unroll
  for (int ot = 0; ot < 4; ++ot) {
    const float bv = bo[w * 64 + ot * 16 + lo];
#pragma unroll
    for (int it = 0; it < 4; ++it) {
      f32x4 r = ya[ot][it];
      r[0] += bv; r[1] += bv; r[2] += bv; r[3] += bv;
      const int tok0 = it * 16 + dg * 4;
      *(f32x4*)(yw + (size_t)(w * 64 + ot * 16 + lo) * 65536 +
                (size_t)(tok0 >> 3) * 256 + (tok0 & 7)) = r;
    }
  }
}

extern "C" void kernel_launch(void* const* d_in, const int* in_sizes, int n_in,
                              void* d_out, int out_size, void* d_ws, size_t ws_size,
                              hipStream_t stream) {
  const float* x = (const float*)d_in[0];
  const float* wqkv = (const float*)d_in[1];
  const float* wout = (const float*)d_in[2];
  const float* bo = (const float*)d_in[3];
  float* y = (float*)d_out;
  unsigned short* wbf = (unsigned short*)d_ws;

  convw_kernel<<<768, 256, 0, stream>>>(wqkv, wout, wbf);
  wattn_kernel<<<4096, 256, 0, stream>>>(x, wbf, wbf + 196608, bo, y);
}